// Round 3
// baseline (256.342 us; speedup 1.0000x reference)
//
#include <hip/hip_runtime.h>

// AttributeDecoder: gather K*S rows (D=256) from features (N,256), per-head
// Linear 256->8 + bias. fp32 in/out, bf16 MFMA compute (threshold permits).
// R3: wave-per-16-s MFMA tiles. Coalesced 1KB row gather (fp32) -> pack to
// bf16 (v_perm) -> wave-private LDS (pitch 264 shorts, bank-balanced) ->
// 8x mfma_f32_16x16x32_bf16 vs register-resident W B-frags (n<8 live).
// No __syncthreads anywhere; tile-1 gathers prefetched during tile-0 compute.

#define KH 24
#define SS 16384
#define VV 8
#define DD 256
#define PITCH 264   // shorts per LDS A-row: 256 + 8 pad (528B = 33*16)

typedef short bf16x8 __attribute__((ext_vector_type(8)));
typedef float f32x4  __attribute__((ext_vector_type(4)));

__device__ __forceinline__ short f32_bf16_rne(float f) {
    unsigned u = __builtin_bit_cast(unsigned, f);
    u = (u + 0x7FFFu + ((u >> 16) & 1u)) >> 16;
    return (short)u;
}

// pack two floats into bf16x2 (round-half-up then truncate), one v_perm
__device__ __forceinline__ int pack_bf16x2(float lo, float hi) {
    unsigned ulo = __builtin_bit_cast(unsigned, lo) + 0x8000u;
    unsigned uhi = __builtin_bit_cast(unsigned, hi) + 0x8000u;
    return __builtin_amdgcn_perm(uhi, ulo, 0x07060302);  // [hi.b3,hi.b2,lo.b3,lo.b2]
}

__global__ __launch_bounds__(256) void attr_decoder_kernel(
    const float* __restrict__ feats,      // (131072, 256)
    const int*   __restrict__ mask_idx,   // (24, 16384)
    const float* __restrict__ head_w,     // (24, 256, 8)
    const float* __restrict__ head_b,     // (24, 8)
    float*       __restrict__ out)        // (24, 16384, 8)
{
    __shared__ short lds[4][16 * PITCH];  // 33792 B, wave-private quarters

    const int lane  = threadIdx.x & 63;
    const int wv    = threadIdx.x >> 6;        // 0..3
    const int k     = blockIdx.x >> 7;         // head
    const int chunk = blockIdx.x & 127;
    const int n     = lane & 15;               // MFMA col (v), live for n<8
    const int q     = lane >> 4;               // quad

    // B fragments: W[k_d][n] in MFMA B layout, bf16, zeros for n>=8.
    // Per lane: step t holds k_d = t*32 + q*8 + j (j=0..7).
    const float* Wk = head_w + (size_t)k * (DD * VV);
    bf16x8 Bf[8];
#pragma unroll
    for (int t = 0; t < 8; ++t) {
#pragma unroll
        for (int j = 0; j < 8; ++j) {
            const int kd = t * 32 + q * 8 + j;
            Bf[t][j] = (n < VV) ? f32_bf16_rne(Wk[kd * VV + n]) : (short)0;
        }
    }
    const float bn = (n < VV) ? head_b[k * VV + n] : 0.f;

    const float4* feats4 = (const float4*)feats;
    const int s_base = chunk * 128 + wv * 32;        // 32 s per wave (2 tiles)
    const int* mi = mask_idx + k * SS + s_base;
    float* outp = out + ((size_t)k * SS + s_base) * VV;
    short* alds = lds[wv];

    // 32 wave-uniform indices
    int rows[32];
#pragma unroll
    for (int c = 0; c < 8; ++c) {
        const int4 r = ((const int4*)mi)[c];
        rows[4 * c + 0] = r.x; rows[4 * c + 1] = r.y;
        rows[4 * c + 2] = r.z; rows[4 * c + 3] = r.w;
    }

    // gather tile 0 (16 coalesced 1KB rows)
    float4 f[16];
#pragma unroll
    for (int j = 0; j < 16; ++j)
        f[j] = feats4[(size_t)rows[j] * 64 + lane];

#pragma unroll
    for (int tile = 0; tile < 2; ++tile) {
        // stage current tile to LDS as bf16 (lane covers d = lane*4..+3)
#pragma unroll
        for (int j = 0; j < 16; ++j) {
            int2 p;
            p.x = pack_bf16x2(f[j].x, f[j].y);
            p.y = pack_bf16x2(f[j].z, f[j].w);
            *(int2*)(alds + j * PITCH + lane * 4) = p;
        }
        // prefetch tile 1 gathers while tile 0 computes
        if (tile == 0) {
#pragma unroll
            for (int j = 0; j < 16; ++j)
                f[j] = feats4[(size_t)rows[16 + j] * 64 + lane];
        }
        // A-frags from LDS + MFMA. a: A[m=n][k=t*32+q*8+j]
        f32x4 acc = {0.f, 0.f, 0.f, 0.f};
#pragma unroll
        for (int t = 0; t < 8; ++t) {
            const bf16x8 a = *(const bf16x8*)(alds + n * PITCH + t * 32 + q * 8);
            acc = __builtin_amdgcn_mfma_f32_16x16x32_bf16(a, Bf[t], acc, 0, 0, 0);
        }
        // store: C[m = q*4+reg][n], m-stride = 8 floats
        if (n < VV) {
            float* op = outp + (size_t)(tile * 16 + q * 4) * VV + n;
            op[0]  = acc[0] + bn;
            op[8]  = acc[1] + bn;
            op[16] = acc[2] + bn;
            op[24] = acc[3] + bn;
        }
    }
}

extern "C" void kernel_launch(void* const* d_in, const int* in_sizes, int n_in,
                              void* d_out, int out_size, void* d_ws, size_t ws_size,
                              hipStream_t stream) {
    // d_in[0] = block_type_grid (unused by reference)
    const float* feats    = (const float*)d_in[1];
    const int*   mask_idx = (const int*)  d_in[2];
    const float* head_w   = (const float*)d_in[3];
    const float* head_b   = (const float*)d_in[4];
    float* out = (float*)d_out;

    dim3 grid(KH * 128);   // 24 heads * 128 chunks; 128 s per block, 32 per wave
    dim3 block(256);
    attr_decoder_kernel<<<grid, block, 0, stream>>>(feats, mask_idx, head_w, head_b, out);
}

// Round 4
// 246.749 us; speedup vs baseline: 1.0389x; 1.0389x over previous
//
#include <hip/hip_runtime.h>

// AttributeDecoder: gather K*S rows (D=256) from features (131072,256),
// per-head Linear 256->8 + bias. fp32 in/out, bf16 MFMA compute.
// R4: MFMA A-frags gathered DIRECTLY from global (no LDS at all).
// Lane (n=lane&15, q=lane>>4) loads rows[n] cols q*8+t*32..+7 as two
// contiguous dwordx4 -> 4 v_perm packs -> mfma_f32_16x16x32_bf16 with
// register-resident W B-frags. Per t-step the MFMA depends only on its own
// 2 loads (fine-grained vmcnt, no lgkmcnt roundtrip, no syncthreads).
// __launch_bounds__(256,8) pins VGPR<=64 -> 8 waves/SIMD.

#define KH 24
#define SS 16384
#define VV 8
#define DD 256

typedef short bf16x8 __attribute__((ext_vector_type(8)));
typedef float f32x4  __attribute__((ext_vector_type(4)));
typedef int   i32x4  __attribute__((ext_vector_type(4)));

__device__ __forceinline__ short f32_bf16_rne(float f) {
    unsigned u = __builtin_bit_cast(unsigned, f);
    u = (u + 0x7FFFu + ((u >> 16) & 1u)) >> 16;
    return (short)u;
}

// two fp32 -> packed bf16x2 (round-half-up), one v_perm
__device__ __forceinline__ unsigned pack_bf16x2(float lo, float hi) {
    unsigned ulo = __builtin_bit_cast(unsigned, lo) + 0x8000u;
    unsigned uhi = __builtin_bit_cast(unsigned, hi) + 0x8000u;
    return __builtin_amdgcn_perm(uhi, ulo, 0x07060302);  // [hi.b3,hi.b2,lo.b3,lo.b2]
}

__global__ __launch_bounds__(256, 8) void attr_decoder_kernel(
    const float* __restrict__ feats,      // (131072, 256)
    const int*   __restrict__ mask_idx,   // (24, 16384)
    const float* __restrict__ head_w,     // (24, 256, 8)
    const float* __restrict__ head_b,     // (24, 8)
    float*       __restrict__ out)        // (24, 16384, 8)
{
    const int lane  = threadIdx.x & 63;
    const int wv    = threadIdx.x >> 6;       // 0..3
    const int k     = blockIdx.x >> 6;        // head (64 chunks/head)
    const int chunk = blockIdx.x & 63;
    const int n     = lane & 15;              // MFMA m (=s within tile) / col n
    const int q     = lane >> 4;              // quad

    // B-frags: Bf[t][j] = W[t*32+q*8+j][n] (bf16), zero for n>=8.
    const float* Wk = head_w + (size_t)k * (DD * VV);
    bf16x8 Bf[8];
#pragma unroll
    for (int t = 0; t < 8; ++t) {
#pragma unroll
        for (int j = 0; j < 8; ++j) {
            const int kd = t * 32 + q * 8 + j;
            Bf[t][j] = (n < VV) ? f32_bf16_rne(Wk[kd * VV + n]) : (short)0;
        }
    }
    const float bn = (n < VV) ? head_b[k * VV + n] : 0.f;

    const int s_base = chunk * 256 + wv * 64;          // 64 s per wave, 4 tiles
    const int* mi = mask_idx + k * SS + s_base;
    float* outp = out + ((size_t)k * SS + s_base) * VV;

    // Each lane keeps only its own tile-row indices (s = tile*16 + n).
    int r[4];
#pragma unroll
    for (int tile = 0; tile < 4; ++tile)
        r[tile] = mi[tile * 16 + n];

#pragma unroll 1
    for (int tile = 0; tile < 4; ++tile) {
        const float* p = feats + (size_t)r[tile] * DD + q * 8;
        f32x4 acc = {0.f, 0.f, 0.f, 0.f};
#pragma unroll
        for (int t = 0; t < 8; ++t) {
            const float4 a0 = *(const float4*)(p + t * 32);
            const float4 a1 = *(const float4*)(p + t * 32 + 4);
            i32x4 ai;
            ai[0] = (int)pack_bf16x2(a0.x, a0.y);
            ai[1] = (int)pack_bf16x2(a0.z, a0.w);
            ai[2] = (int)pack_bf16x2(a1.x, a1.y);
            ai[3] = (int)pack_bf16x2(a1.z, a1.w);
            const bf16x8 a = __builtin_bit_cast(bf16x8, ai);
            acc = __builtin_amdgcn_mfma_f32_16x16x32_bf16(a, Bf[t], acc, 0, 0, 0);
        }
        // C[m][n]: m = q*4 + reg (validated layout), m-stride = 8 floats
        if (n < VV) {
            float* op = outp + (size_t)(tile * 16 + q * 4) * VV + n;
            op[0]  = acc[0] + bn;
            op[8]  = acc[1] + bn;
            op[16] = acc[2] + bn;
            op[24] = acc[3] + bn;
        }
    }
}

extern "C" void kernel_launch(void* const* d_in, const int* in_sizes, int n_in,
                              void* d_out, int out_size, void* d_ws, size_t ws_size,
                              hipStream_t stream) {
    // d_in[0] = block_type_grid (unused by reference)
    const float* feats    = (const float*)d_in[1];
    const int*   mask_idx = (const int*)  d_in[2];
    const float* head_w   = (const float*)d_in[3];
    const float* head_b   = (const float*)d_in[4];
    float* out = (float*)d_out;

    dim3 grid(KH * 64);   // 24 heads * 64 chunks; 256 s/block, 64 s/wave
    dim3 block(256);
    attr_decoder_kernel<<<grid, block, 0, stream>>>(feats, mask_idx, head_w, head_b, out);
}